// Round 11
// baseline (11511.888 us; speedup 1.0000x reference)
//
#include <hip/hip_runtime.h>

// CharRNN: 3-layer shared-weight LSTM (H=65) over T=4096, B=50, + dense head.
//
// Round-11: FUSED cell update, ONE barrier/round.
//   8-lane group per cell n; lane j = side(W/U) x k-quarter q. Thread owns all
//   4 gate columns of its cell for its (side, rows 16q..16q+15 [+row64 q==3]):
//   68 weights, looped over 3 layers (shared weights). 12 DPP adds give every
//   lane the 4 full z's -> activations + c (register, replicated) + h computed
//   in place; lane j==0 publishes h (1 ds_write_b32). No s_z, no Phase B, no
//   second barrier. h/x are parity double-buffered (write 1-p, read p).
//   R10 lesson: per-column overhead dominates -> fewer, fatter columns/thread.

#define HH    65
#define G4    260
#define TT    4096
#define NB    50
#define BLOCK 640
#define NMAIN 520
#define DROWS 64

using v2f = __attribute__((ext_vector_type(2))) float;
#define PKFMA(a, b, c) __builtin_elementwise_fma((a), (b), (c))
#define KEEP(s) asm volatile("" : "+v"(s))

__device__ __forceinline__ float sigm(float x)  { return 1.0f / (1.0f + __expf(-x)); }
__device__ __forceinline__ float tanha(float x) { float e = __expf(2.0f * x); return 1.0f - 2.0f / (e + 1.0f); }

// sum across 8-lane group (lane bits 0-2): quad xor1, quad xor2, half-row mirror
__device__ __forceinline__ float qsum8(float v) {
    int i = __float_as_int(v);
    v += __int_as_float(__builtin_amdgcn_update_dpp(0, i, 0xB1,  0xF, 0xF, true));
    i = __float_as_int(v);
    v += __int_as_float(__builtin_amdgcn_update_dpp(0, i, 0x4E,  0xF, 0xF, true));
    i = __float_as_int(v);
    v += __int_as_float(__builtin_amdgcn_update_dpp(0, i, 0x141, 0xF, 0xF, true));
    return v;
}

__global__ void __launch_bounds__(BLOCK)
__attribute__((amdgpu_waves_per_eu(2, 3)))
charrnn_rec(const float* __restrict__ x, const float* __restrict__ W,
            const float* __restrict__ U, const float* __restrict__ bv,
            float* __restrict__ out)
{
    __shared__ __align__(16) float s_h[3][2][68];  // [layer][parity][cell]; [65..67] unused
    __shared__ __align__(16) float s_x[2][68];     // x(t) staging, parity-buffered

    const int bat = blockIdx.x, tid = threadIdx.x;
    const float* xb   = x   + (size_t)bat * TT * HH;
    float*       outb = out + (size_t)bat * TT * HH;

    for (int i = tid; i < 3 * 2 * 68; i += BLOCK) (&s_h[0][0][0])[i] = 0.0f;

    const bool isM  = (tid < NMAIN);
    const int  n    = tid >> 3;          // cell 0..64
    const int  j    = tid & 7;
    const int  side = j >> 2;            // 0 = W (input side), 1 = U (recurrent side)
    const int  q    = j & 3;             // k-quarter: rows 16q..16q+15 (+row 64 if q==3)
    const int  kst  = 16 * q;
    const float* M  = side ? U : W;

    // 4 gate columns (n+65g) x 16 rows as 8 v2f each + row-64 scalar (q==3)
    v2f wA0, wA1, wA2, wA3, wA4, wA5, wA6, wA7,
        wB0, wB1, wB2, wB3, wB4, wB5, wB6, wB7,
        wC0, wC1, wC2, wC3, wC4, wC5, wC6, wC7,
        wD0, wD1, wD2, wD3, wD4, wD5, wD6, wD7;
#define WLD(v, g, pp)                                                         \
    do {                                                                      \
        float t0 = isM ? M[(kst + 2 * (pp) + 0) * G4 + n + 65 * (g)] : 0.0f;  \
        float t1 = isM ? M[(kst + 2 * (pp) + 1) * G4 + n + 65 * (g)] : 0.0f;  \
        KEEP(t0); KEEP(t1);                                                   \
        v = (v2f){t0, t1};                                                    \
    } while (0)
    WLD(wA0, 0, 0); WLD(wA1, 0, 1); WLD(wA2, 0, 2); WLD(wA3, 0, 3);
    WLD(wA4, 0, 4); WLD(wA5, 0, 5); WLD(wA6, 0, 6); WLD(wA7, 0, 7);
    WLD(wB0, 1, 0); WLD(wB1, 1, 1); WLD(wB2, 1, 2); WLD(wB3, 1, 3);
    WLD(wB4, 1, 4); WLD(wB5, 1, 5); WLD(wB6, 1, 6); WLD(wB7, 1, 7);
    WLD(wC0, 2, 0); WLD(wC1, 2, 1); WLD(wC2, 2, 2); WLD(wC3, 2, 3);
    WLD(wC4, 2, 4); WLD(wC5, 2, 5); WLD(wC6, 2, 6); WLD(wC7, 2, 7);
    WLD(wD0, 3, 0); WLD(wD1, 3, 1); WLD(wD2, 3, 2); WLD(wD3, 3, 3);
    WLD(wD4, 3, 4); WLD(wD5, 3, 5); WLD(wD6, 3, 6); WLD(wD7, 3, 7);
#undef WLD
    const bool hasTail = isM && (q == 3);
    float wsA = hasTail ? M[64 * G4 + n]           : 0.0f; KEEP(wsA);
    float wsB = hasTail ? M[64 * G4 + n + 65]      : 0.0f; KEEP(wsB);
    float wsC = hasTail ? M[64 * G4 + n + 130]     : 0.0f; KEEP(wsC);
    float wsD = hasTail ? M[64 * G4 + n + 195]     : 0.0f; KEEP(wsD);

    const float bz0 = isM ? bv[n]       : 0.0f;
    const float bz1 = isM ? bv[65 + n]  : 0.0f;
    const float bz2 = isM ? bv[130 + n] : 0.0f;
    const float bz3 = isM ? bv[195 + n] : 0.0f;

    // x prefetch: tids 576..639 -> pidx 0..63; tid 520 -> pidx 64
    const int pidx = (tid >= 576) ? (tid - 576) : ((tid == NMAIN) ? 64 : -1);
    float cur = 0.0f, nxt = 0.0f;
    if (pidx >= 0) {
        s_x[0][pidx] = xb[pidx];        // x(0)
        cur = xb[HH + pidx];            // x(1)
    }

    float creg0 = 0.0f, creg1 = 0.0f, creg2 = 0.0f;
    int p = 0;
    __syncthreads();

    for (int r = 0; r < TT + 2; ++r) {
        if (pidx >= 0) {   // issue x(r+2) early; latency hidden under FMAs
            const int tn = r + 2;
            nxt = (tn < TT) ? xb[(size_t)tn * HH + pidx] : 0.0f;
        }
        if (isM) {
#pragma unroll
            for (int l = 0; l < 3; ++l) {
                if ((unsigned)(r - l) < TT) {
                    const float* hb = side ? &s_h[l][p][0]
                                           : (l == 0 ? &s_x[p][0] : &s_h[l - 1][p][0]);
                    const float4* h4 = (const float4*)(hb + kst);
                    const float4 H0 = h4[0], H1 = h4[1], H2 = h4[2], H3 = h4[3];
                    const float  h64 = hb[64];
                    const v2f hA = (v2f){H0.x, H0.y}, hB = (v2f){H0.z, H0.w},
                              hC = (v2f){H1.x, H1.y}, hD = (v2f){H1.z, H1.w},
                              hE = (v2f){H2.x, H2.y}, hF = (v2f){H2.z, H2.w},
                              hG = (v2f){H3.x, H3.y}, hHv = (v2f){H3.z, H3.w};
                    float a0, a1, a2, a3;
#define CD(res, P0, P1, P2, P3, P4, P5, P6, P7, S)                            \
    {   v2f ac = hA * P0;                                                     \
        ac = PKFMA(hB, P1, ac);  ac = PKFMA(hC, P2, ac);                      \
        ac = PKFMA(hD, P3, ac);  ac = PKFMA(hE, P4, ac);                      \
        ac = PKFMA(hF, P5, ac);  ac = PKFMA(hG, P6, ac);                      \
        ac = PKFMA(hHv, P7, ac);                                              \
        res = fmaf(h64, S, ac.x + ac.y); }
                    CD(a0, wA0, wA1, wA2, wA3, wA4, wA5, wA6, wA7, wsA)
                    CD(a1, wB0, wB1, wB2, wB3, wB4, wB5, wB6, wB7, wsB)
                    CD(a2, wC0, wC1, wC2, wC3, wC4, wC5, wC6, wC7, wsC)
                    CD(a3, wD0, wD1, wD2, wD3, wD4, wD5, wD6, wD7, wsD)
#undef CD
                    const float z0 = qsum8(a0) + bz0;
                    const float z1 = qsum8(a1) + bz1;
                    const float z2 = qsum8(a2) + bz2;
                    const float z3 = qsum8(a3) + bz3;
                    const float ig = sigm(z0), fg = sigm(z1),
                                gg = tanha(z2), og = sigm(z3);
                    float c;
                    if (l == 0)      { creg0 = fmaf(fg, creg0, ig * gg); c = creg0; }
                    else if (l == 1) { creg1 = fmaf(fg, creg1, ig * gg); c = creg1; }
                    else             { creg2 = fmaf(fg, creg2, ig * gg); c = creg2; }
                    const float h = og * tanha(c);
                    if (j == 0) {
                        s_h[l][p ^ 1][n] = h;
                        if (l == 2) outb[(size_t)(r - 2) * HH + n] = h;
                    }
                }
            }
        }
        if (pidx >= 0) {
            if (r + 1 < TT) s_x[p ^ 1][pidx] = cur;
            cur = nxt;
        }
        __syncthreads();
        p ^= 1;
    }
}

// ---- kernel 2: in-place dense head over d_out: y = h2 @ Wd + bd ----
__global__ void __launch_bounds__(256, 1)
dense_head(float* __restrict__ io, const float* __restrict__ Wd, const float* __restrict__ bd)
{
    __shared__ __align__(16) float s_h[DROWS][68];
    __shared__ float s_wd[HH][HH];
    __shared__ float s_bd[HH];

    const int tid = threadIdx.x;
    float* base = io + (size_t)blockIdx.x * DROWS * HH;

    for (int i = tid; i < DROWS * HH; i += 256) {
        const int row = i / HH, k = i - row * HH;
        s_h[row][k] = base[i];
    }
    for (int i = tid; i < HH * HH; i += 256) (&s_wd[0][0])[i] = Wd[i];
    if (tid < HH) s_bd[tid] = bd[tid];
    __syncthreads();

    for (int u = tid; u < DROWS * HH; u += 256) {
        const int row = u / HH, c = u - row * HH;
        const float4* hp = (const float4*)&s_h[row][0];
        float acc = s_bd[c];
#pragma unroll
        for (int k4 = 0; k4 < 16; ++k4) {
            const float4 hv = hp[k4];
            acc = fmaf(hv.x, s_wd[4 * k4 + 0][c], acc);
            acc = fmaf(hv.y, s_wd[4 * k4 + 1][c], acc);
            acc = fmaf(hv.z, s_wd[4 * k4 + 2][c], acc);
            acc = fmaf(hv.w, s_wd[4 * k4 + 3][c], acc);
        }
        acc = fmaf(s_h[row][64], s_wd[64][c], acc);
        base[u] = acc;   // safe: all reads come from LDS copies
    }
}

extern "C" void kernel_launch(void* const* d_in, const int* in_sizes, int n_in,
                              void* d_out, int out_size, void* d_ws, size_t ws_size,
                              hipStream_t stream)
{
    const float* x  = (const float*)d_in[0];
    const float* W  = (const float*)d_in[1];
    const float* U  = (const float*)d_in[2];
    const float* bv = (const float*)d_in[3];
    const float* Wd = (const float*)d_in[4];
    const float* bd = (const float*)d_in[5];
    float* out = (float*)d_out;

    hipLaunchKernelGGL(charrnn_rec, dim3(NB), dim3(BLOCK), 0, stream, x, W, U, bv, out);
    hipLaunchKernelGGL(dense_head, dim3(NB * TT / DROWS), dim3(256), 0, stream, out, Wd, bd);
}

// Round 12
// 11274.742 us; speedup vs baseline: 1.0210x; 1.0210x over previous
//
#include <hip/hip_runtime.h>

// CharRNN: 3-layer shared-weight LSTM (H=65) over T=4096, B=50, + dense head.
//
// Round-12: TWO SEQUENCES PER BLOCK on the proven R9 structure (25 blocks).
//   R9 counters: 3470 cyc/round = 1850 issue + 1620 exposed stalls (2 barrier
//   drains, LDS latency at phase heads, DPP/activation chains, Phase B on only
//   3/8 waves). Weights are shared across sequences -> the same 68 register
//   floats serve both seqs; per-round stalls are paid once for two sequences.
//   R10/R11 lesson: v2f packing and >100-float live sets spill (VGPR 52/56);
//   R9's scalar-KEEP float4 at need~90 is the only allocator-honored config.

#define HH    65
#define G4    260
#define TT    4096
#define NBLK  25
#define BLOCK 512
#define DROWS 64

#define KEEP4(v) asm volatile("" : "+v"(v.x), "+v"(v.y), "+v"(v.z), "+v"(v.w))
#define KEEP(s)  asm volatile("" : "+v"(s))

__device__ __forceinline__ float sigm(float x)  { return 1.0f / (1.0f + __expf(-x)); }
__device__ __forceinline__ float tanha(float x) { float e = __expf(2.0f * x); return 1.0f - 2.0f / (e + 1.0f); }

// sum across the 4 lanes of a quad (lane bits 0-1) via DPP; all 4 lanes get total
__device__ __forceinline__ float qsum(float v) {
    int i = __float_as_int(v);
    v += __int_as_float(__builtin_amdgcn_update_dpp(0, i, 0xB1, 0xF, 0xF, true)); // [1,0,3,2]
    i = __float_as_int(v);
    v += __int_as_float(__builtin_amdgcn_update_dpp(0, i, 0x4E, 0xF, 0xF, true)); // [2,3,0,1]
    return v;
}

__global__ void __launch_bounds__(BLOCK)
__attribute__((amdgpu_waves_per_eu(2, 2)))
charrnn_rec(const float* __restrict__ x, const float* __restrict__ W,
            const float* __restrict__ U, const float* __restrict__ bv,
            float* __restrict__ out)
{
    __shared__ __align__(16) float s_hin[2][3][68];    // [seq][layer][cell]; row0 = x(t)
    __shared__ __align__(16) float s_hrec[2][3][68];   // [seq][layer][cell]
    __shared__ __align__(16) float s_z[2][3][2][256];  // [seq][layer][side][col]
    __shared__ float s_parte[2][3][2][4];              // [seq][layer][side][col-256]

    const int tid = threadIdx.x;
    const float* xb0 = x + (size_t)(2 * blockIdx.x)     * TT * HH;
    const float* xb1 = x + (size_t)(2 * blockIdx.x + 1) * TT * HH;
    float* outb0 = out + (size_t)(2 * blockIdx.x)     * TT * HH;
    float* outb1 = out + (size_t)(2 * blockIdx.x + 1) * TT * HH;

    for (int i = tid; i < 2 * 3 * 68; i += BLOCK) { (&s_hin[0][0][0])[i] = 0.0f; (&s_hrec[0][0][0])[i] = 0.0f; }

    const int w    = tid & 3;             // k-window: rows 16w..16w+15 (+ row 64 on w==3)
    const int side = tid >> 8;            // 0 = W (reads hin), 1 = U (reads hrec)
    const int qL   = (tid >> 2) & 63;     // column quad within side
    const int col0 = qL * 4;              // cols col0..col0+3
    const float* M = side ? U : W;

    // 16 float4 weights (shared across both sequences) — R9-proven spelling
    float4 wa0, wa1, wa2, wa3, wb0, wb1, wb2, wb3,
           wc0, wc1, wc2, wc3, wd0, wd1, wd2, wd3;
#define WLD(v, c, q)                                                          \
    do {                                                                      \
        v.x = M[(16 * w + 4 * (q) + 0) * G4 + col0 + (c)];                    \
        v.y = M[(16 * w + 4 * (q) + 1) * G4 + col0 + (c)];                    \
        v.z = M[(16 * w + 4 * (q) + 2) * G4 + col0 + (c)];                    \
        v.w = M[(16 * w + 4 * (q) + 3) * G4 + col0 + (c)];                    \
        KEEP4(v);                                                             \
    } while (0)
    WLD(wa0, 0, 0); WLD(wa1, 0, 1); WLD(wa2, 0, 2); WLD(wa3, 0, 3);
    WLD(wb0, 1, 0); WLD(wb1, 1, 1); WLD(wb2, 1, 2); WLD(wb3, 1, 3);
    WLD(wc0, 2, 0); WLD(wc1, 2, 1); WLD(wc2, 2, 2); WLD(wc3, 2, 3);
    WLD(wd0, 3, 0); WLD(wd1, 3, 1); WLD(wd2, 3, 2); WLD(wd3, 3, 3);
#undef WLD
    float ws0 = (w == 3) ? M[64 * G4 + col0 + 0] : 0.0f; KEEP(ws0);
    float ws1 = (w == 3) ? M[64 * G4 + col0 + 1] : 0.0f; KEEP(ws1);
    float ws2 = (w == 3) ? M[64 * G4 + col0 + 2] : 0.0f; KEEP(ws2);
    float ws3 = (w == 3) ? M[64 * G4 + col0 + 3] : 0.0f; KEEP(ws3);

    // extra cols 256..259 (o-gate cells 61..64): lanes (tid&255)<16, both sides
    const bool isX  = ((tid & 255) < 16);
    const int  colX = 256 + ((tid >> 2) & 3);
    float4 e0, e1, e2, e3;
#define ELD(v, q)                                                             \
    do {                                                                      \
        v.x = isX ? M[(16 * w + 4 * (q) + 0) * G4 + colX] : 0.0f;             \
        v.y = isX ? M[(16 * w + 4 * (q) + 1) * G4 + colX] : 0.0f;             \
        v.z = isX ? M[(16 * w + 4 * (q) + 2) * G4 + colX] : 0.0f;             \
        v.w = isX ? M[(16 * w + 4 * (q) + 3) * G4 + colX] : 0.0f;             \
        KEEP4(v);                                                             \
    } while (0)
    ELD(e0, 0); ELD(e1, 1); ELD(e2, 2); ELD(e3, 3);
#undef ELD
    float esc = (isX && w == 3) ? M[64 * G4 + colX] : 0.0f; KEEP(esc);

    // cell role (tid < 195): biases in registers; one creg per sequence
    const int  cl = tid / 65, n = tid - (tid / 65) * 65;
    const bool isC = (tid < 195);
    const float bz0 = bv[n], bz1 = bv[65 + n], bz2 = bv[130 + n], bz3 = bv[195 + n];
    float cregA = 0.0f, cregB = 0.0f;

    // x prefetch: tids 382..446 -> seq0 idx 0..64; tids 447..511 -> seq1 idx 0..64
    const bool isP  = (tid >= 382);
    const int  pseq = (tid >= 447) ? 1 : 0;
    const int  pidx = tid - 382 - 65 * pseq;
    const float* xbp = pseq ? xb1 : xb0;
    float cur = 0.0f, nxt = 0.0f;
    if (isP) {
        s_hin[pseq][0][pidx] = xbp[pidx];   // x(0)
        cur = xbp[HH + pidx];               // x(1)
    }
    __syncthreads();

    for (int r = 0; r < TT + 2; ++r) {
        // ---------------- Phase A ----------------
        if (isP) {  // issue x(r+2) early; latency hidden under gate FMAs
            const int tn = r + 2;
            nxt = (tn < TT) ? xbp[(size_t)tn * HH + pidx] : 0.0f;
        }
#define COLDOT(acc, p0, p1, p2, p3, ps)                                       \
    {   float u0, u1;                                                         \
        u0 = H0.x * p0.x;           u1 = H0.y * p0.y;                         \
        u0 = fmaf(H0.z, p0.z, u0);  u1 = fmaf(H0.w, p0.w, u1);                \
        u0 = fmaf(H1.x, p1.x, u0);  u1 = fmaf(H1.y, p1.y, u1);                \
        u0 = fmaf(H1.z, p1.z, u0);  u1 = fmaf(H1.w, p1.w, u1);                \
        u0 = fmaf(H2.x, p2.x, u0);  u1 = fmaf(H2.y, p2.y, u1);                \
        u0 = fmaf(H2.z, p2.z, u0);  u1 = fmaf(H2.w, p2.w, u1);                \
        u0 = fmaf(H3.x, p3.x, u0);  u1 = fmaf(H3.y, p3.y, u1);                \
        u0 = fmaf(H3.z, p3.z, u0);  u1 = fmaf(H3.w, p3.w, u1);                \
        u0 = fmaf(h64, ps, u0);                                               \
        acc = u0 + u1; }
#define SEQA(ss)                                                              \
    {   const float* hb = side ? &s_hrec[ss][l][0] : &s_hin[ss][l][0];        \
        const float4* h4 = (const float4*)(hb + 16 * w);                      \
        const float4 H0 = h4[0], H1 = h4[1], H2 = h4[2], H3 = h4[3];          \
        const float  h64 = hb[64];                                            \
        float a0, a1, a2, a3;                                                 \
        COLDOT(a0, wa0, wa1, wa2, wa3, ws0)                                   \
        COLDOT(a1, wb0, wb1, wb2, wb3, ws1)                                   \
        COLDOT(a2, wc0, wc1, wc2, wc3, ws2)                                   \
        COLDOT(a3, wd0, wd1, wd2, wd3, ws3)                                   \
        a0 = qsum(a0); a1 = qsum(a1); a2 = qsum(a2); a3 = qsum(a3);           \
        if (w == 0)                                                           \
            *(float4*)&s_z[ss][l][side][col0] = make_float4(a0, a1, a2, a3);  \
        if (isX) {                                                            \
            float ea;                                                         \
            COLDOT(ea, e0, e1, e2, e3, esc)                                   \
            ea = qsum(ea);                                                    \
            if (w == 0) s_parte[ss][l][side][(tid >> 2) & 3] = ea;            \
        } }
#pragma unroll
        for (int l = 0; l < 3; ++l) {
            if ((unsigned)(r - l) < TT) {
                SEQA(0)
                SEQA(1)
            }
        }
#undef SEQA
#undef COLDOT
        __syncthreads();

        // ---------------- Phase B: cell updates, both sequences ----------------
        if (isC) {
            if ((unsigned)(r - cl) < TT) {
#define CELLB(ss, cregv, outbp)                                               \
    {   const float zi = bz0 + s_z[ss][cl][0][n]       + s_z[ss][cl][1][n];   \
        const float zf = bz1 + s_z[ss][cl][0][65 + n]  + s_z[ss][cl][1][65 + n];  \
        const float zg = bz2 + s_z[ss][cl][0][130 + n] + s_z[ss][cl][1][130 + n]; \
        float zo;                                                             \
        if (n < 61) zo = bz3 + s_z[ss][cl][0][195 + n]     + s_z[ss][cl][1][195 + n];  \
        else        zo = bz3 + s_parte[ss][cl][0][n - 61]  + s_parte[ss][cl][1][n - 61]; \
        const float ig = sigm(zi), fg = sigm(zf), gg = tanha(zg), og = sigm(zo); \
        cregv = fmaf(fg, cregv, ig * gg);                                     \
        const float h = og * tanha(cregv);                                    \
        s_hrec[ss][cl][n] = h;                                                \
        if (cl < 2) s_hin[ss][cl + 1][n] = h;                                 \
        else        outbp[(size_t)(r - cl) * HH + n] = h; }
                CELLB(0, cregA, outb0)
                CELLB(1, cregB, outb1)
#undef CELLB
            }
        }
        if (isP) {
            if (r + 1 < TT) s_hin[pseq][0][pidx] = cur;
            cur = nxt;
        }
        __syncthreads();
    }
}

// ---- kernel 2: in-place dense head over d_out: y = h2 @ Wd + bd ----
__global__ void __launch_bounds__(256, 1)
dense_head(float* __restrict__ io, const float* __restrict__ Wd, const float* __restrict__ bd)
{
    __shared__ __align__(16) float s_h[DROWS][68];
    __shared__ float s_wd[HH][HH];
    __shared__ float s_bd[HH];

    const int tid = threadIdx.x;
    float* base = io + (size_t)blockIdx.x * DROWS * HH;

    for (int i = tid; i < DROWS * HH; i += 256) {
        const int row = i / HH, k = i - row * HH;
        s_h[row][k] = base[i];
    }
    for (int i = tid; i < HH * HH; i += 256) (&s_wd[0][0])[i] = Wd[i];
    if (tid < HH) s_bd[tid] = bd[tid];
    __syncthreads();

    for (int u = tid; u < DROWS * HH; u += 256) {
        const int row = u / HH, c = u - row * HH;
        const float4* hp = (const float4*)&s_h[row][0];
        float acc = s_bd[c];
#pragma unroll
        for (int k4 = 0; k4 < 16; ++k4) {
            const float4 hv = hp[k4];
            acc = fmaf(hv.x, s_wd[4 * k4 + 0][c], acc);
            acc = fmaf(hv.y, s_wd[4 * k4 + 1][c], acc);
            acc = fmaf(hv.z, s_wd[4 * k4 + 2][c], acc);
            acc = fmaf(hv.w, s_wd[4 * k4 + 3][c], acc);
        }
        acc = fmaf(s_h[row][64], s_wd[64][c], acc);
        base[u] = acc;   // safe: all reads come from LDS copies
    }
}

extern "C" void kernel_launch(void* const* d_in, const int* in_sizes, int n_in,
                              void* d_out, int out_size, void* d_ws, size_t ws_size,
                              hipStream_t stream)
{
    const float* x  = (const float*)d_in[0];
    const float* W  = (const float*)d_in[1];
    const float* U  = (const float*)d_in[2];
    const float* bv = (const float*)d_in[3];
    const float* Wd = (const float*)d_in[4];
    const float* bd = (const float*)d_in[5];
    float* out = (float*)d_out;

    hipLaunchKernelGGL(charrnn_rec, dim3(NBLK), dim3(BLOCK), 0, stream, x, W, U, bv, out);
    hipLaunchKernelGGL(dense_head, dim3(50 * TT / DROWS), dim3(256), 0, stream, out, Wd, bd);
}

// Round 13
// 5974.075 us; speedup vs baseline: 1.9270x; 1.8873x over previous
//
#include <hip/hip_runtime.h>

// CharRNN: 3-layer shared-weight LSTM (H=65) over T=4096, B=50, + dense head.
//
// Round-13: R9 structure EXACTLY (50 blocks x 512 thr, 2 waves/SIMD, thread =
//   4 cols x 16-row window, DPP quad reduction, 2 barriers) with the 72
//   scalar FMAs per thread-layer replaced by 36 v_pk_fma_f32.
//   R12 lesson: stall scales with issue (busy% ~const 53%) -> cutting issue is
//   the lever. R10/R11 packed-math spills traced to KEEP on v2f COMPONENTS
//   (scalar constraints broke 64-bit pairing); here KEEP binds the whole v2f
//   as one 64-bit asm operand so pairs survive allocation.

#define HH    65
#define G4    260
#define TT    4096
#define NB    50
#define BLOCK 512
#define DROWS 64

using v2f = __attribute__((ext_vector_type(2))) float;
#define PKFMA(a, b, c) __builtin_elementwise_fma((a), (b), (c))
#define KEEPV(v) asm volatile("" : "+v"(v))   // v2f: one 64-bit operand, keeps pairing
#define KEEP(s)  asm volatile("" : "+v"(s))

__device__ __forceinline__ float sigm(float x)  { return 1.0f / (1.0f + __expf(-x)); }
__device__ __forceinline__ float tanha(float x) { float e = __expf(2.0f * x); return 1.0f - 2.0f / (e + 1.0f); }

// sum across the 4 lanes of a quad (lane bits 0-1) via DPP; all 4 lanes get total
__device__ __forceinline__ float qsum(float v) {
    int i = __float_as_int(v);
    v += __int_as_float(__builtin_amdgcn_update_dpp(0, i, 0xB1, 0xF, 0xF, true)); // [1,0,3,2]
    i = __float_as_int(v);
    v += __int_as_float(__builtin_amdgcn_update_dpp(0, i, 0x4E, 0xF, 0xF, true)); // [2,3,0,1]
    return v;
}

__global__ void __launch_bounds__(BLOCK)
__attribute__((amdgpu_waves_per_eu(2, 2)))
charrnn_rec(const float* __restrict__ x, const float* __restrict__ W,
            const float* __restrict__ U, const float* __restrict__ bv,
            float* __restrict__ out)
{
    __shared__ __align__(16) float s_hin[3][68];    // input to layer l (row0 = x(t)); [65..67]=0
    __shared__ __align__(16) float s_hrec[3][68];   // recurrent h per layer
    __shared__ __align__(16) float s_z[3][2][256];  // [layer][side][col] full dots, cols 0..255
    __shared__ float s_parte[3][2][4];              // [layer][side][col-256] dots, cols 256..259

    const int bat = blockIdx.x;
    const int tid = threadIdx.x;
    const float* xb   = x   + (size_t)bat * TT * HH;
    float*       outb = out + (size_t)bat * TT * HH;

    for (int i = tid; i < 3 * 68; i += BLOCK) { (&s_hin[0][0])[i] = 0.0f; (&s_hrec[0][0])[i] = 0.0f; }

    const int w    = tid & 3;             // k-window: rows 16w..16w+15 (+ row 64 on w==3)
    const int side = tid >> 8;            // 0 = W (reads hin), 1 = U (reads hrec)
    const int qL   = (tid >> 2) & 63;     // column quad within side
    const int col0 = qL * 4;              // cols col0..col0+3 (0..255)
    const float* M = side ? U : W;

    // 32 v2f weights: col c, row-pair p -> M[16w+2p .. +1][col0+c]; tail scalar on w==3
    v2f wa0, wa1, wa2, wa3, wa4, wa5, wa6, wa7,
        wb0, wb1, wb2, wb3, wb4, wb5, wb6, wb7,
        wc0, wc1, wc2, wc3, wc4, wc5, wc6, wc7,
        wd0, wd1, wd2, wd3, wd4, wd5, wd6, wd7;
#define WLD(v, c, p)                                                          \
    do {                                                                      \
        v = (v2f){ M[(16 * w + 2 * (p) + 0) * G4 + col0 + (c)],               \
                   M[(16 * w + 2 * (p) + 1) * G4 + col0 + (c)] };             \
        KEEPV(v);                                                             \
    } while (0)
    WLD(wa0, 0, 0); WLD(wa1, 0, 1); WLD(wa2, 0, 2); WLD(wa3, 0, 3);
    WLD(wa4, 0, 4); WLD(wa5, 0, 5); WLD(wa6, 0, 6); WLD(wa7, 0, 7);
    WLD(wb0, 1, 0); WLD(wb1, 1, 1); WLD(wb2, 1, 2); WLD(wb3, 1, 3);
    WLD(wb4, 1, 4); WLD(wb5, 1, 5); WLD(wb6, 1, 6); WLD(wb7, 1, 7);
    WLD(wc0, 2, 0); WLD(wc1, 2, 1); WLD(wc2, 2, 2); WLD(wc3, 2, 3);
    WLD(wc4, 2, 4); WLD(wc5, 2, 5); WLD(wc6, 2, 6); WLD(wc7, 2, 7);
    WLD(wd0, 3, 0); WLD(wd1, 3, 1); WLD(wd2, 3, 2); WLD(wd3, 3, 3);
    WLD(wd4, 3, 4); WLD(wd5, 3, 5); WLD(wd6, 3, 6); WLD(wd7, 3, 7);
#undef WLD
    float ws0 = (w == 3) ? M[64 * G4 + col0 + 0] : 0.0f; KEEP(ws0);
    float ws1 = (w == 3) ? M[64 * G4 + col0 + 1] : 0.0f; KEEP(ws1);
    float ws2 = (w == 3) ? M[64 * G4 + col0 + 2] : 0.0f; KEEP(ws2);
    float ws3 = (w == 3) ? M[64 * G4 + col0 + 3] : 0.0f; KEEP(ws3);

    // extra cols 256..259: lanes (tid&255)<16, both sides
    const bool isX  = ((tid & 255) < 16);
    const int  colX = 256 + ((tid >> 2) & 3);
    v2f e0, e1, e2, e3, e4, e5, e6, e7;
#define ELD(v, p)                                                             \
    do {                                                                      \
        v = (v2f){ isX ? M[(16 * w + 2 * (p) + 0) * G4 + colX] : 0.0f,        \
                   isX ? M[(16 * w + 2 * (p) + 1) * G4 + colX] : 0.0f };      \
        KEEPV(v);                                                             \
    } while (0)
    ELD(e0, 0); ELD(e1, 1); ELD(e2, 2); ELD(e3, 3);
    ELD(e4, 4); ELD(e5, 5); ELD(e6, 6); ELD(e7, 7);
#undef ELD
    float esc = (isX && w == 3) ? M[64 * G4 + colX] : 0.0f; KEEP(esc);

    // cell role (tid < 195): biases pre-loaded to registers
    const int  cl = tid / 65, n = tid - (tid / 65) * 65;
    const bool isC = (tid < 195);
    const float bz0 = bv[n], bz1 = bv[65 + n], bz2 = bv[130 + n], bz3 = bv[195 + n];
    float creg = 0.0f;

    // x prefetch: tids 447..511 -> pidx 0..64
    const bool isP  = (tid >= 447);
    const int  pidx = tid - 447;
    float cur = 0.0f, nxt = 0.0f;
    if (isP) {
        s_hin[0][pidx] = xb[pidx];      // x(0)
        cur = xb[HH + pidx];            // x(1)
    }
    __syncthreads();

    for (int r = 0; r < TT + 2; ++r) {
        // ---------------- Phase A ----------------
        if (isP) {  // issue x(r+2) early
            const int tn = r + 2;
            nxt = (tn < TT) ? xb[(size_t)tn * HH + pidx] : 0.0f;
        }
#pragma unroll
        for (int l = 0; l < 3; ++l) {
            if ((unsigned)(r - l) < TT) {
                const float* hb = side ? &s_hrec[l][0] : &s_hin[l][0];
                const float4* h4 = (const float4*)(hb + 16 * w);   // 16B aligned
                const float4 H0 = h4[0], H1 = h4[1], H2 = h4[2], H3 = h4[3];
                const float  h64 = hb[64];                          // broadcast b32
                const v2f hA = (v2f){H0.x, H0.y}, hB = (v2f){H0.z, H0.w};
                const v2f hC = (v2f){H1.x, H1.y}, hD = (v2f){H1.z, H1.w};
                const v2f hE = (v2f){H2.x, H2.y}, hF = (v2f){H2.z, H2.w};
                const v2f hG = (v2f){H3.x, H3.y}, hHv = (v2f){H3.z, H3.w};
                float a0, a1, a2, a3;
#define COLDOT(acc, p0, p1, p2, p3, p4, p5, p6, p7, ps)                       \
    {   v2f ac = hA * p0;                                                     \
        ac = PKFMA(hB, p1, ac);  ac = PKFMA(hC, p2, ac);                      \
        ac = PKFMA(hD, p3, ac);  ac = PKFMA(hE, p4, ac);                      \
        ac = PKFMA(hF, p5, ac);  ac = PKFMA(hG, p6, ac);                      \
        ac = PKFMA(hHv, p7, ac);                                              \
        acc = fmaf(h64, ps, ac.x + ac.y); }
                COLDOT(a0, wa0, wa1, wa2, wa3, wa4, wa5, wa6, wa7, ws0)
                COLDOT(a1, wb0, wb1, wb2, wb3, wb4, wb5, wb6, wb7, ws1)
                COLDOT(a2, wc0, wc1, wc2, wc3, wc4, wc5, wc6, wc7, ws2)
                COLDOT(a3, wd0, wd1, wd2, wd3, wd4, wd5, wd6, wd7, ws3)
                a0 = qsum(a0); a1 = qsum(a1); a2 = qsum(a2); a3 = qsum(a3);
                if (w == 0)
                    *(float4*)&s_z[l][side][col0] = make_float4(a0, a1, a2, a3);
                if (isX) {
                    float ea;
                    COLDOT(ea, e0, e1, e2, e3, e4, e5, e6, e7, esc)
                    ea = qsum(ea);
                    if (w == 0) s_parte[l][side][(tid >> 2) & 3] = ea;
                }
#undef COLDOT
            }
        }
        __syncthreads();

        // ---------------- Phase B: cell updates ----------------
        if (isC) {
            if ((unsigned)(r - cl) < TT) {
                const float zi = bz0 + s_z[cl][0][n]       + s_z[cl][1][n];
                const float zf = bz1 + s_z[cl][0][65 + n]  + s_z[cl][1][65 + n];
                const float zg = bz2 + s_z[cl][0][130 + n] + s_z[cl][1][130 + n];
                float zo;
                if (n < 61) zo = bz3 + s_z[cl][0][195 + n]    + s_z[cl][1][195 + n];
                else        zo = bz3 + s_parte[cl][0][n - 61] + s_parte[cl][1][n - 61];
                const float ig = sigm(zi), fg = sigm(zf), gg = tanha(zg), og = sigm(zo);
                creg = fmaf(fg, creg, ig * gg);
                const float h = og * tanha(creg);
                s_hrec[cl][n] = h;
                if (cl < 2) s_hin[cl + 1][n] = h;
                else        outb[(size_t)(r - cl) * HH + n] = h;   // stream h2 to out
            }
        }
        if (isP) {
            if (r + 1 < TT) s_hin[0][pidx] = cur;
            cur = nxt;
        }
        __syncthreads();
    }
}

// ---- kernel 2: in-place dense head over d_out: y = h2 @ Wd + bd ----
__global__ void __launch_bounds__(256, 1)
dense_head(float* __restrict__ io, const float* __restrict__ Wd, const float* __restrict__ bd)
{
    __shared__ __align__(16) float s_h[DROWS][68];
    __shared__ float s_wd[HH][HH];
    __shared__ float s_bd[HH];

    const int tid = threadIdx.x;
    float* base = io + (size_t)blockIdx.x * DROWS * HH;

    for (int i = tid; i < DROWS * HH; i += 256) {
        const int row = i / HH, k = i - row * HH;
        s_h[row][k] = base[i];
    }
    for (int i = tid; i < HH * HH; i += 256) (&s_wd[0][0])[i] = Wd[i];
    if (tid < HH) s_bd[tid] = bd[tid];
    __syncthreads();

    for (int u = tid; u < DROWS * HH; u += 256) {
        const int row = u / HH, c = u - row * HH;
        const float4* hp = (const float4*)&s_h[row][0];
        float acc = s_bd[c];
#pragma unroll
        for (int k4 = 0; k4 < 16; ++k4) {
            const float4 hv = hp[k4];
            acc = fmaf(hv.x, s_wd[4 * k4 + 0][c], acc);
            acc = fmaf(hv.y, s_wd[4 * k4 + 1][c], acc);
            acc = fmaf(hv.z, s_wd[4 * k4 + 2][c], acc);
            acc = fmaf(hv.w, s_wd[4 * k4 + 3][c], acc);
        }
        acc = fmaf(s_h[row][64], s_wd[64][c], acc);
        base[u] = acc;   // safe: all reads come from LDS copies
    }
}

extern "C" void kernel_launch(void* const* d_in, const int* in_sizes, int n_in,
                              void* d_out, int out_size, void* d_ws, size_t ws_size,
                              hipStream_t stream)
{
    const float* x  = (const float*)d_in[0];
    const float* W  = (const float*)d_in[1];
    const float* U  = (const float*)d_in[2];
    const float* bv = (const float*)d_in[3];
    const float* Wd = (const float*)d_in[4];
    const float* bd = (const float*)d_in[5];
    float* out = (float*)d_out;

    hipLaunchKernelGGL(charrnn_rec, dim3(NB), dim3(BLOCK), 0, stream, x, W, U, bv, out);
    hipLaunchKernelGGL(dense_head, dim3(NB * TT / DROWS), dim3(256), 0, stream, out, Wd, bd);
}

// Round 14
// 5937.107 us; speedup vs baseline: 1.9390x; 1.0062x over previous
//
#include <hip/hip_runtime.h>

// CharRNN: 3-layer shared-weight LSTM (H=65) over T=4096, B=50, + dense head.
//
// Round-14: R13 structure EXACTLY, but packed math FORCED via inline asm.
//   R13's null (same dur AND same VALUBusy as scalar R9) proves
//   __builtin_elementwise_fma was scalarized — v_pk_fma_f32 never emitted.
//   Here: v_pk_mul_f32 / v_pk_fma_f32 (tied "+v" accumulator, v2f = 64-bit
//   pair). Cuts ~96 scalar FMAs/thread-round -> per-SIMD issue 1840->~1300.
//   Decisive: if stall~issue (R12), dur -> 4.4-4.9ms; if unchanged with
//   busy dropping to ~7.5, kernel is latency-bound -> R15 fuses Phase B.

#define HH    65
#define G4    260
#define TT    4096
#define NB    50
#define BLOCK 512
#define DROWS 64

using v2f = __attribute__((ext_vector_type(2))) float;
#define KEEPV(v) asm volatile("" : "+v"(v))   // v2f: one 64-bit operand, keeps pairing
#define KEEP(s)  asm volatile("" : "+v"(s))

#define PKMUL(d, a, b) \
    asm("v_pk_mul_f32 %0, %1, %2" : "=v"(d) : "v"(a), "v"(b))
#define PKFMAACC(acc, a, b) \
    asm("v_pk_fma_f32 %0, %1, %2, %0" : "+v"(acc) : "v"(a), "v"(b))

__device__ __forceinline__ float sigm(float x)  { return 1.0f / (1.0f + __expf(-x)); }
__device__ __forceinline__ float tanha(float x) { float e = __expf(2.0f * x); return 1.0f - 2.0f / (e + 1.0f); }

// sum across the 4 lanes of a quad (lane bits 0-1) via DPP; all 4 lanes get total
__device__ __forceinline__ float qsum(float v) {
    int i = __float_as_int(v);
    v += __int_as_float(__builtin_amdgcn_update_dpp(0, i, 0xB1, 0xF, 0xF, true)); // [1,0,3,2]
    i = __float_as_int(v);
    v += __int_as_float(__builtin_amdgcn_update_dpp(0, i, 0x4E, 0xF, 0xF, true)); // [2,3,0,1]
    return v;
}

__global__ void __launch_bounds__(BLOCK)
__attribute__((amdgpu_waves_per_eu(2, 2)))
charrnn_rec(const float* __restrict__ x, const float* __restrict__ W,
            const float* __restrict__ U, const float* __restrict__ bv,
            float* __restrict__ out)
{
    __shared__ __align__(16) float s_hin[3][68];    // input to layer l (row0 = x(t)); [65..67]=0
    __shared__ __align__(16) float s_hrec[3][68];   // recurrent h per layer
    __shared__ __align__(16) float s_z[3][2][256];  // [layer][side][col] full dots, cols 0..255
    __shared__ float s_parte[3][2][4];              // [layer][side][col-256] dots, cols 256..259

    const int bat = blockIdx.x;
    const int tid = threadIdx.x;
    const float* xb   = x   + (size_t)bat * TT * HH;
    float*       outb = out + (size_t)bat * TT * HH;

    for (int i = tid; i < 3 * 68; i += BLOCK) { (&s_hin[0][0])[i] = 0.0f; (&s_hrec[0][0])[i] = 0.0f; }

    const int w    = tid & 3;             // k-window: rows 16w..16w+15 (+ row 64 on w==3)
    const int side = tid >> 8;            // 0 = W (reads hin), 1 = U (reads hrec)
    const int qL   = (tid >> 2) & 63;     // column quad within side
    const int col0 = qL * 4;              // cols col0..col0+3 (0..255)
    const float* M = side ? U : W;

    // 32 v2f weights: col c, row-pair p -> M[16w+2p .. +1][col0+c]; tail scalar on w==3
    v2f wa0, wa1, wa2, wa3, wa4, wa5, wa6, wa7,
        wb0, wb1, wb2, wb3, wb4, wb5, wb6, wb7,
        wc0, wc1, wc2, wc3, wc4, wc5, wc6, wc7,
        wd0, wd1, wd2, wd3, wd4, wd5, wd6, wd7;
#define WLD(v, c, p)                                                          \
    do {                                                                      \
        v = (v2f){ M[(16 * w + 2 * (p) + 0) * G4 + col0 + (c)],               \
                   M[(16 * w + 2 * (p) + 1) * G4 + col0 + (c)] };             \
        KEEPV(v);                                                             \
    } while (0)
    WLD(wa0, 0, 0); WLD(wa1, 0, 1); WLD(wa2, 0, 2); WLD(wa3, 0, 3);
    WLD(wa4, 0, 4); WLD(wa5, 0, 5); WLD(wa6, 0, 6); WLD(wa7, 0, 7);
    WLD(wb0, 1, 0); WLD(wb1, 1, 1); WLD(wb2, 1, 2); WLD(wb3, 1, 3);
    WLD(wb4, 1, 4); WLD(wb5, 1, 5); WLD(wb6, 1, 6); WLD(wb7, 1, 7);
    WLD(wc0, 2, 0); WLD(wc1, 2, 1); WLD(wc2, 2, 2); WLD(wc3, 2, 3);
    WLD(wc4, 2, 4); WLD(wc5, 2, 5); WLD(wc6, 2, 6); WLD(wc7, 2, 7);
    WLD(wd0, 3, 0); WLD(wd1, 3, 1); WLD(wd2, 3, 2); WLD(wd3, 3, 3);
    WLD(wd4, 3, 4); WLD(wd5, 3, 5); WLD(wd6, 3, 6); WLD(wd7, 3, 7);
#undef WLD
    float ws0 = (w == 3) ? M[64 * G4 + col0 + 0] : 0.0f; KEEP(ws0);
    float ws1 = (w == 3) ? M[64 * G4 + col0 + 1] : 0.0f; KEEP(ws1);
    float ws2 = (w == 3) ? M[64 * G4 + col0 + 2] : 0.0f; KEEP(ws2);
    float ws3 = (w == 3) ? M[64 * G4 + col0 + 3] : 0.0f; KEEP(ws3);

    // extra cols 256..259: lanes (tid&255)<16, both sides
    const bool isX  = ((tid & 255) < 16);
    const int  colX = 256 + ((tid >> 2) & 3);
    v2f e0, e1, e2, e3, e4, e5, e6, e7;
#define ELD(v, p)                                                             \
    do {                                                                      \
        v = (v2f){ isX ? M[(16 * w + 2 * (p) + 0) * G4 + colX] : 0.0f,        \
                   isX ? M[(16 * w + 2 * (p) + 1) * G4 + colX] : 0.0f };      \
        KEEPV(v);                                                             \
    } while (0)
    ELD(e0, 0); ELD(e1, 1); ELD(e2, 2); ELD(e3, 3);
    ELD(e4, 4); ELD(e5, 5); ELD(e6, 6); ELD(e7, 7);
#undef ELD
    float esc = (isX && w == 3) ? M[64 * G4 + colX] : 0.0f; KEEP(esc);

    // cell role (tid < 195): biases pre-loaded to registers
    const int  cl = tid / 65, n = tid - (tid / 65) * 65;
    const bool isC = (tid < 195);
    const float bz0 = bv[n], bz1 = bv[65 + n], bz2 = bv[130 + n], bz3 = bv[195 + n];
    float creg = 0.0f;

    // x prefetch: tids 447..511 -> pidx 0..64
    const bool isP  = (tid >= 447);
    const int  pidx = tid - 447;
    float cur = 0.0f, nxt = 0.0f;
    if (isP) {
        s_hin[0][pidx] = xb[pidx];      // x(0)
        cur = xb[HH + pidx];            // x(1)
    }
    __syncthreads();

    for (int r = 0; r < TT + 2; ++r) {
        // ---------------- Phase A ----------------
        if (isP) {  // issue x(r+2) early
            const int tn = r + 2;
            nxt = (tn < TT) ? xb[(size_t)tn * HH + pidx] : 0.0f;
        }
#pragma unroll
        for (int l = 0; l < 3; ++l) {
            if ((unsigned)(r - l) < TT) {
                const float* hb = side ? &s_hrec[l][0] : &s_hin[l][0];
                const float4* h4 = (const float4*)(hb + 16 * w);   // 16B aligned
                const float4 H0 = h4[0], H1 = h4[1], H2 = h4[2], H3 = h4[3];
                const float  h64 = hb[64];                          // broadcast b32
                const v2f hA = (v2f){H0.x, H0.y}, hB = (v2f){H0.z, H0.w};
                const v2f hC = (v2f){H1.x, H1.y}, hD = (v2f){H1.z, H1.w};
                const v2f hE = (v2f){H2.x, H2.y}, hF = (v2f){H2.z, H2.w};
                const v2f hG = (v2f){H3.x, H3.y}, hHv = (v2f){H3.z, H3.w};
                float a0, a1, a2, a3;
#define COLDOT(acc, p0, p1, p2, p3, p4, p5, p6, p7, ps)                       \
    {   v2f ac;                                                               \
        PKMUL(ac, hA, p0);                                                    \
        PKFMAACC(ac, hB, p1);  PKFMAACC(ac, hC, p2);                          \
        PKFMAACC(ac, hD, p3);  PKFMAACC(ac, hE, p4);                          \
        PKFMAACC(ac, hF, p5);  PKFMAACC(ac, hG, p6);                          \
        PKFMAACC(ac, hHv, p7);                                                \
        acc = fmaf(h64, ps, ac.x + ac.y); }
                COLDOT(a0, wa0, wa1, wa2, wa3, wa4, wa5, wa6, wa7, ws0)
                COLDOT(a1, wb0, wb1, wb2, wb3, wb4, wb5, wb6, wb7, ws1)
                COLDOT(a2, wc0, wc1, wc2, wc3, wc4, wc5, wc6, wc7, ws2)
                COLDOT(a3, wd0, wd1, wd2, wd3, wd4, wd5, wd6, wd7, ws3)
                a0 = qsum(a0); a1 = qsum(a1); a2 = qsum(a2); a3 = qsum(a3);
                if (w == 0)
                    *(float4*)&s_z[l][side][col0] = make_float4(a0, a1, a2, a3);
                if (isX) {
                    float ea;
                    COLDOT(ea, e0, e1, e2, e3, e4, e5, e6, e7, esc)
                    ea = qsum(ea);
                    if (w == 0) s_parte[l][side][(tid >> 2) & 3] = ea;
                }
#undef COLDOT
            }
        }
        __syncthreads();

        // ---------------- Phase B: cell updates ----------------
        if (isC) {
            if ((unsigned)(r - cl) < TT) {
                const float zi = bz0 + s_z[cl][0][n]       + s_z[cl][1][n];
                const float zf = bz1 + s_z[cl][0][65 + n]  + s_z[cl][1][65 + n];
                const float zg = bz2 + s_z[cl][0][130 + n] + s_z[cl][1][130 + n];
                float zo;
                if (n < 61) zo = bz3 + s_z[cl][0][195 + n]    + s_z[cl][1][195 + n];
                else        zo = bz3 + s_parte[cl][0][n - 61] + s_parte[cl][1][n - 61];
                const float ig = sigm(zi), fg = sigm(zf), gg = tanha(zg), og = sigm(zo);
                creg = fmaf(fg, creg, ig * gg);
                const float h = og * tanha(creg);
                s_hrec[cl][n] = h;
                if (cl < 2) s_hin[cl + 1][n] = h;
                else        outb[(size_t)(r - cl) * HH + n] = h;   // stream h2 to out
            }
        }
        if (isP) {
            if (r + 1 < TT) s_hin[0][pidx] = cur;
            cur = nxt;
        }
        __syncthreads();
    }
}

// ---- kernel 2: in-place dense head over d_out: y = h2 @ Wd + bd ----
__global__ void __launch_bounds__(256, 1)
dense_head(float* __restrict__ io, const float* __restrict__ Wd, const float* __restrict__ bd)
{
    __shared__ __align__(16) float s_h[DROWS][68];
    __shared__ float s_wd[HH][HH];
    __shared__ float s_bd[HH];

    const int tid = threadIdx.x;
    float* base = io + (size_t)blockIdx.x * DROWS * HH;

    for (int i = tid; i < DROWS * HH; i += 256) {
        const int row = i / HH, k = i - row * HH;
        s_h[row][k] = base[i];
    }
    for (int i = tid; i < HH * HH; i += 256) (&s_wd[0][0])[i] = Wd[i];
    if (tid < HH) s_bd[tid] = bd[tid];
    __syncthreads();

    for (int u = tid; u < DROWS * HH; u += 256) {
        const int row = u / HH, c = u - row * HH;
        const float4* hp = (const float4*)&s_h[row][0];
        float acc = s_bd[c];
#pragma unroll
        for (int k4 = 0; k4 < 16; ++k4) {
            const float4 hv = hp[k4];
            acc = fmaf(hv.x, s_wd[4 * k4 + 0][c], acc);
            acc = fmaf(hv.y, s_wd[4 * k4 + 1][c], acc);
            acc = fmaf(hv.z, s_wd[4 * k4 + 2][c], acc);
            acc = fmaf(hv.w, s_wd[4 * k4 + 3][c], acc);
        }
        acc = fmaf(s_h[row][64], s_wd[64][c], acc);
        base[u] = acc;   // safe: all reads come from LDS copies
    }
}

extern "C" void kernel_launch(void* const* d_in, const int* in_sizes, int n_in,
                              void* d_out, int out_size, void* d_ws, size_t ws_size,
                              hipStream_t stream)
{
    const float* x  = (const float*)d_in[0];
    const float* W  = (const float*)d_in[1];
    const float* U  = (const float*)d_in[2];
    const float* bv = (const float*)d_in[3];
    const float* Wd = (const float*)d_in[4];
    const float* bd = (const float*)d_in[5];
    float* out = (float*)d_out;

    hipLaunchKernelGGL(charrnn_rec, dim3(NB), dim3(BLOCK), 0, stream, x, W, U, bv, out);
    hipLaunchKernelGGL(dense_head, dim3(NB * TT / DROWS), dim3(256), 0, stream, out, Wd, bd);
}